// Round 1
// baseline (1555.803 us; speedup 1.0000x reference)
//
#include <hip/hip_runtime.h>

// Problem constants: B=4096, T=512, IN=32, H=[64,64,128], OUT=10
// d_in order: x, Wih0, Whh0, bih0, bhh0, Wih1, Whh1, bih1, bhh1,
//             Wih2, Whh2, bih2, bhh2, Wfc, bfc

using f32x4  = __attribute__((ext_vector_type(4))) float;
using bf16x8 = __attribute__((ext_vector_type(8))) __bf16;

__device__ __forceinline__ __bf16 f2bf(float f) {
  unsigned u = __builtin_bit_cast(unsigned, f);
  unsigned short s = (unsigned short)((u + 0x7fffu + ((u >> 16) & 1u)) >> 16);
  return __builtin_bit_cast(__bf16, s);
}
__device__ __forceinline__ float bf2f(__bf16 b) {
  unsigned short s = __builtin_bit_cast(unsigned short, b);
  unsigned u = ((unsigned)s) << 16;
  return __builtin_bit_cast(float, u);
}
__device__ __forceinline__ float fsig(float x) {
  return __builtin_amdgcn_rcpf(1.0f + __builtin_amdgcn_exp2f(-1.442695041f * x));
}
__device__ __forceinline__ float ftanh(float x) {
  return 2.0f * __builtin_amdgcn_rcpf(1.0f + __builtin_amdgcn_exp2f(-2.885390082f * x)) - 1.0f;
}

// ---------------- prep: bf16 weight repack + bias sums ----------------
// ws layout (elements):
//   wcat0: bf16 [256][96]   (Wih0 | Whh0)      24576
//   wcat1: bf16 [256][128]  (Wih1 | Whh1)      32768
//   wih2b: bf16 [512][64]   (Wih2)             32768
//   bsum : f32  [1024]      (bs0[256],bs1[256],bs2[512])
__global__ void prep_kernel(const float* __restrict__ Wih0, const float* __restrict__ Whh0,
                            const float* __restrict__ bih0, const float* __restrict__ bhh0,
                            const float* __restrict__ Wih1, const float* __restrict__ Whh1,
                            const float* __restrict__ bih1, const float* __restrict__ bhh1,
                            const float* __restrict__ Wih2,
                            const float* __restrict__ bih2, const float* __restrict__ bhh2,
                            __bf16* __restrict__ wcat0, __bf16* __restrict__ wcat1,
                            __bf16* __restrict__ wih2b, float* __restrict__ bsum) {
  int i = blockIdx.x * 256 + threadIdx.x;
  if (i < 24576) { int g = i / 96, k = i - g * 96;
    wcat0[i] = f2bf(k < 32 ? Wih0[g * 32 + k] : Whh0[g * 64 + (k - 32)]); return; }
  i -= 24576;
  if (i < 32768) { int g = i >> 7, k = i & 127;
    wcat1[i] = f2bf(k < 64 ? Wih1[g * 64 + k] : Whh1[g * 64 + (k - 64)]); return; }
  i -= 32768;
  if (i < 32768) { wih2b[i] = f2bf(Wih2[i]); return; }
  i -= 32768;
  if (i < 256) { bsum[i] = bih0[i] + bhh0[i]; return; }
  i -= 256;
  if (i < 256) { bsum[256 + i] = bih1[i] + bhh1[i]; return; }
  i -= 256;
  if (i < 512) { bsum[512 + i] = bih2[i] + bhh2[i]; return; }
}

// ---------------- main persistent LSTM kernel ----------------
#define MF(A, Bv, C) __builtin_amdgcn_mfma_f32_16x16x32_bf16((A), (Bv), (C), 0, 0, 0)

__global__ __launch_bounds__(256, 1)
void lstm_kernel(const float* __restrict__ x, const float* __restrict__ Whh2,
                 const __bf16* __restrict__ wcat0, const __bf16* __restrict__ wcat1,
                 const __bf16* __restrict__ wih2b, const float* __restrict__ bsum,
                 const float* __restrict__ Wfc, const float* __restrict__ bfc,
                 float* __restrict__ out) {
  // h state (bf16, padded rows: stride 72/136 shorts -> 2-way bank aliasing only)
  __shared__ __align__(16) __bf16 h0s[16][72];
  __shared__ __align__(16) __bf16 h1s[16][72];
  __shared__ __align__(16) __bf16 h2s[16][136];
  // Whh2 staged bf16 [512][136] (row pad 8)
  __shared__ __align__(16) __bf16 whh2s[512 * 136];

  const int tid = threadIdx.x;
  const int w   = tid >> 6;   // wave 0..3
  const int l   = tid & 63;
  const int l15 = l & 15;
  const int lg  = l >> 4;     // 0..3
  const int r0  = blockIdx.x << 4;

  for (int i = tid; i < 512 * 128; i += 256) {
    int row = i >> 7, col = i & 127;
    whh2s[row * 136 + col] = f2bf(Whh2[i]);
  }
  for (int i = tid; i < 16 * 72; i += 256) { (&h0s[0][0])[i] = f2bf(0.f); (&h1s[0][0])[i] = f2bf(0.f); }
  for (int i = tid; i < 16 * 136; i += 256) (&h2s[0][0])[i] = f2bf(0.f);

  // biases (col = 16*tile + l15); gate blocks i,f,g,o
  float bias0[4], bias1[4], bias2[2][4];
#pragma unroll
  for (int gi = 0; gi < 4; ++gi) {
    bias0[gi] = bsum[gi * 64 + 16 * w + l15];
    bias1[gi] = bsum[256 + gi * 64 + 16 * w + l15];
  }
#pragma unroll
  for (int s = 0; s < 2; ++s)
#pragma unroll
    for (int gi = 0; gi < 4; ++gi)
      bias2[s][gi] = bsum[512 + gi * 128 + 32 * w + 16 * s + l15];

  float c0v[4] = {0.f, 0.f, 0.f, 0.f};
  float c1v[4] = {0.f, 0.f, 0.f, 0.f};
  float c2v[2][4] = {{0.f, 0.f, 0.f, 0.f}, {0.f, 0.f, 0.f, 0.f}};

  __syncthreads();

  const float* xblk = x + (size_t)r0 * (512 * 32);

#define BF_G(base, Kc, tile, kb) \
  (*(const bf16x8*)((base) + (size_t)(16 * (tile) + l15) * (Kc) + (kb) * 32 + lg * 8))
#define BF_L(tile, kk) \
  (*(const bf16x8*)(whh2s + (16 * (tile) + l15) * 136 + (kk) * 32 + lg * 8))

  for (int t = 0; t < 512; ++t) {
    // ================= layer 0 =================
    bf16x8 ax;
    {
      const float* xp = xblk + ((size_t)l15 * 512 + (size_t)t) * 32 + lg * 8;
      float4 v0 = *(const float4*)xp;
      float4 v1 = *(const float4*)(xp + 4);
      ax[0] = f2bf(v0.x); ax[1] = f2bf(v0.y); ax[2] = f2bf(v0.z); ax[3] = f2bf(v0.w);
      ax[4] = f2bf(v1.x); ax[5] = f2bf(v1.y); ax[6] = f2bf(v1.z); ax[7] = f2bf(v1.w);
    }
    bf16x8 a0 = *(const bf16x8*)&h0s[l15][lg * 8];
    bf16x8 a1 = *(const bf16x8*)&h0s[l15][32 + lg * 8];

    f32x4 acc[4];
#pragma unroll
    for (int gi = 0; gi < 4; ++gi) {
      const int tile = 4 * gi + w;
      f32x4 a = {bias0[gi], bias0[gi], bias0[gi], bias0[gi]};
      a = MF(ax, BF_G(wcat0, 96, tile, 0), a);
      a = MF(a0, BF_G(wcat0, 96, tile, 1), a);
      a = MF(a1, BF_G(wcat0, 96, tile, 2), a);
      acc[gi] = a;
    }
    __syncthreads();  // all reads of h0(t-1) done
#pragma unroll
    for (int j = 0; j < 4; ++j) {
      float nc = fsig(acc[1][j]) * c0v[j] + fsig(acc[0][j]) * ftanh(acc[2][j]);
      c0v[j] = nc;
      h0s[4 * lg + j][16 * w + l15] = f2bf(fsig(acc[3][j]) * ftanh(nc));
    }
    __syncthreads();  // h0(t) visible

    // ================= layer 1 =================
    a0 = *(const bf16x8*)&h0s[l15][lg * 8];
    a1 = *(const bf16x8*)&h0s[l15][32 + lg * 8];
    bf16x8 a2 = *(const bf16x8*)&h1s[l15][lg * 8];
    bf16x8 a3 = *(const bf16x8*)&h1s[l15][32 + lg * 8];
#pragma unroll
    for (int gi = 0; gi < 4; ++gi) {
      const int tile = 4 * gi + w;
      f32x4 a = {bias1[gi], bias1[gi], bias1[gi], bias1[gi]};
      a = MF(a0, BF_G(wcat1, 128, tile, 0), a);
      a = MF(a1, BF_G(wcat1, 128, tile, 1), a);
      a = MF(a2, BF_G(wcat1, 128, tile, 2), a);
      a = MF(a3, BF_G(wcat1, 128, tile, 3), a);
      acc[gi] = a;
    }
    __syncthreads();
#pragma unroll
    for (int j = 0; j < 4; ++j) {
      float nc = fsig(acc[1][j]) * c1v[j] + fsig(acc[0][j]) * ftanh(acc[2][j]);
      c1v[j] = nc;
      h1s[4 * lg + j][16 * w + l15] = f2bf(fsig(acc[3][j]) * ftanh(nc));
    }
    __syncthreads();

    // ================= layer 2 =================
    a0 = *(const bf16x8*)&h1s[l15][lg * 8];
    a1 = *(const bf16x8*)&h1s[l15][32 + lg * 8];
    bf16x8 d0 = *(const bf16x8*)&h2s[l15][lg * 8];
    bf16x8 d1 = *(const bf16x8*)&h2s[l15][32 + lg * 8];
    bf16x8 d2 = *(const bf16x8*)&h2s[l15][64 + lg * 8];
    bf16x8 d3 = *(const bf16x8*)&h2s[l15][96 + lg * 8];
    f32x4 acc2[2][4];
#pragma unroll
    for (int s = 0; s < 2; ++s) {
#pragma unroll
      for (int gi = 0; gi < 4; ++gi) {
        const int tile = 8 * gi + 2 * w + s;
        f32x4 a = {bias2[s][gi], bias2[s][gi], bias2[s][gi], bias2[s][gi]};
        a = MF(a0, BF_G(wih2b, 64, tile, 0), a);
        a = MF(a1, BF_G(wih2b, 64, tile, 1), a);
        a = MF(d0, BF_L(tile, 0), a);
        a = MF(d1, BF_L(tile, 1), a);
        a = MF(d2, BF_L(tile, 2), a);
        a = MF(d3, BF_L(tile, 3), a);
        acc2[s][gi] = a;
      }
    }
    __syncthreads();
#pragma unroll
    for (int s = 0; s < 2; ++s) {
#pragma unroll
      for (int j = 0; j < 4; ++j) {
        float nc = fsig(acc2[s][1][j]) * c2v[s][j] + fsig(acc2[s][0][j]) * ftanh(acc2[s][2][j]);
        c2v[s][j] = nc;
        h2s[4 * lg + j][32 * w + 16 * s + l15] = f2bf(fsig(acc2[s][3][j]) * ftanh(nc));
      }
    }
    __syncthreads();
  }

  // ================= final FC: out = h2 @ Wfc^T + bfc =================
  if (tid < 160) {
    const int r = tid / 10, o = tid - r * 10;
    float sum = bfc[o];
    for (int u = 0; u < 128; ++u) sum += bf2f(h2s[r][u]) * Wfc[o * 128 + u];
    out[(size_t)(r0 + r) * 10 + o] = sum;
  }
}

extern "C" void kernel_launch(void* const* d_in, const int* in_sizes, int n_in,
                              void* d_out, int out_size, void* d_ws, size_t ws_size,
                              hipStream_t stream) {
  const float* x    = (const float*)d_in[0];
  const float* Wih0 = (const float*)d_in[1];
  const float* Whh0 = (const float*)d_in[2];
  const float* bih0 = (const float*)d_in[3];
  const float* bhh0 = (const float*)d_in[4];
  const float* Wih1 = (const float*)d_in[5];
  const float* Whh1 = (const float*)d_in[6];
  const float* bih1 = (const float*)d_in[7];
  const float* bhh1 = (const float*)d_in[8];
  const float* Wih2 = (const float*)d_in[9];
  const float* Whh2 = (const float*)d_in[10];
  const float* bih2 = (const float*)d_in[11];
  const float* bhh2 = (const float*)d_in[12];
  const float* Wfc  = (const float*)d_in[13];
  const float* bfc  = (const float*)d_in[14];

  __bf16* wcat0 = (__bf16*)d_ws;            // 24576 bf16
  __bf16* wcat1 = wcat0 + 24576;            // 32768 bf16
  __bf16* wih2b = wcat1 + 32768;            // 32768 bf16
  float*  bsum  = (float*)(wih2b + 32768);  // 1024 f32

  prep_kernel<<<356, 256, 0, stream>>>(Wih0, Whh0, bih0, bhh0, Wih1, Whh1, bih1, bhh1,
                                       Wih2, bih2, bhh2, wcat0, wcat1, wih2b, bsum);
  lstm_kernel<<<256, 256, 0, stream>>>(x, Whh2, wcat0, wcat1, wih2b, bsum, Wfc, bfc,
                                       (float*)d_out);
}

// Round 2
// 1201.868 us; speedup vs baseline: 1.2945x; 1.2945x over previous
//
#include <hip/hip_runtime.h>

// B=4096, T=512, IN=32, H=[64,64,128], OUT=10
// d_in: x, Wih0, Whh0, bih0, bhh0, Wih1, Whh1, bih1, bhh1, Wih2, Whh2, bih2, bhh2, Wfc, bfc
//
// Strategy: 256 blocks (1/CU) x 256 threads (4 waves = 1 wave/SIMD -> full 512-VGPR
// budget). Each wave holds ITS slice of ALL weights in 304 VGPRs (bf16). h states
// double-buffered in LDS -> 3 barriers/step. x prefetched one step ahead.

using f32x4  = __attribute__((ext_vector_type(4))) float;
using bf16x8 = __attribute__((ext_vector_type(8))) __bf16;

__device__ __forceinline__ __bf16 f2bf(float f) {
  unsigned u = __builtin_bit_cast(unsigned, f);
  unsigned short s = (unsigned short)((u + 0x7fffu + ((u >> 16) & 1u)) >> 16);
  return __builtin_bit_cast(__bf16, s);
}
__device__ __forceinline__ float bf2f(__bf16 b) {
  unsigned short s = __builtin_bit_cast(unsigned short, b);
  unsigned u = ((unsigned)s) << 16;
  return __builtin_bit_cast(float, u);
}
__device__ __forceinline__ float fsig(float x) {
  return __builtin_amdgcn_rcpf(1.0f + __builtin_amdgcn_exp2f(-1.442695041f * x));
}
__device__ __forceinline__ float ftanh(float x) {
  return 2.0f * __builtin_amdgcn_rcpf(1.0f + __builtin_amdgcn_exp2f(-2.885390082f * x)) - 1.0f;
}

#define MF(A, Bv, C) __builtin_amdgcn_mfma_f32_16x16x32_bf16((A), (Bv), (C), 0, 0, 0)

__device__ __forceinline__ bf16x8 ldw8(const float* p) {
  float4 v0 = *(const float4*)p;
  float4 v1 = *(const float4*)(p + 4);
  bf16x8 r;
  r[0] = f2bf(v0.x); r[1] = f2bf(v0.y); r[2] = f2bf(v0.z); r[3] = f2bf(v0.w);
  r[4] = f2bf(v1.x); r[5] = f2bf(v1.y); r[6] = f2bf(v1.z); r[7] = f2bf(v1.w);
  return r;
}

__global__ __launch_bounds__(256, 1)
void lstm_kernel(const float* __restrict__ x,
                 const float* __restrict__ Wih0, const float* __restrict__ Whh0,
                 const float* __restrict__ bih0, const float* __restrict__ bhh0,
                 const float* __restrict__ Wih1, const float* __restrict__ Whh1,
                 const float* __restrict__ bih1, const float* __restrict__ bhh1,
                 const float* __restrict__ Wih2, const float* __restrict__ Whh2,
                 const float* __restrict__ bih2, const float* __restrict__ bhh2,
                 const float* __restrict__ Wfc, const float* __restrict__ bfc,
                 float* __restrict__ out) {
  // double-buffered h states; row stride 72/136 shorts (pad 8) -> benign bank aliasing
  __shared__ __align__(16) __bf16 h0s[2][16][72];
  __shared__ __align__(16) __bf16 h1s[2][16][72];
  __shared__ __align__(16) __bf16 h2s[2][16][136];

  const int tid = threadIdx.x;
  const int w   = tid >> 6;   // wave 0..3
  const int l   = tid & 63;
  const int l15 = l & 15;
  const int lg  = l >> 4;     // 0..3
  const int k0  = lg * 8;
  const int r0  = blockIdx.x << 4;

  for (int i = tid; i < 2 * 16 * 72; i += 256) {
    (&h0s[0][0][0])[i] = f2bf(0.f);
    (&h1s[0][0][0])[i] = f2bf(0.f);
  }
  for (int i = tid; i < 2 * 16 * 136; i += 256) (&h2s[0][0][0])[i] = f2bf(0.f);

  // ---- hoist this wave's weight slice into registers (304 VGPRs bf16) ----
  bf16x8 W0x[4];        // Wih0 [gi], tile=4gi+w, C=32
  bf16x8 W0h[4][2];     // Whh0 [gi][kb], C=64
  bf16x8 W1a[4][2];     // Wih1 [gi][kb], C=64
  bf16x8 W1h[4][2];     // Whh1 [gi][kb], C=64
  bf16x8 W2a[2][4][2];  // Wih2 [s][gi][kb], tile=8gi+2w+s, C=64
  bf16x8 W2h[2][4][4];  // Whh2 [s][gi][kk], C=128
#pragma unroll
  for (int gi = 0; gi < 4; ++gi) {
    const int row = 16 * (4 * gi + w) + l15;
    W0x[gi] = ldw8(Wih0 + (size_t)row * 32 + k0);
#pragma unroll
    for (int kb = 0; kb < 2; ++kb) {
      W0h[gi][kb] = ldw8(Whh0 + (size_t)row * 64 + kb * 32 + k0);
      W1a[gi][kb] = ldw8(Wih1 + (size_t)row * 64 + kb * 32 + k0);
      W1h[gi][kb] = ldw8(Whh1 + (size_t)row * 64 + kb * 32 + k0);
    }
  }
#pragma unroll
  for (int s = 0; s < 2; ++s)
#pragma unroll
    for (int gi = 0; gi < 4; ++gi) {
      const int row = 16 * (8 * gi + 2 * w + s) + l15;
#pragma unroll
      for (int kb = 0; kb < 2; ++kb)
        W2a[s][gi][kb] = ldw8(Wih2 + (size_t)row * 64 + kb * 32 + k0);
#pragma unroll
      for (int kk = 0; kk < 4; ++kk)
        W2h[s][gi][kk] = ldw8(Whh2 + (size_t)row * 128 + kk * 32 + k0);
    }

  float bias0[4], bias1[4], bias2[2][4];
#pragma unroll
  for (int gi = 0; gi < 4; ++gi) {
    const int c01 = 64 * gi + 16 * w + l15;
    bias0[gi] = bih0[c01] + bhh0[c01];
    bias1[gi] = bih1[c01] + bhh1[c01];
  }
#pragma unroll
  for (int s = 0; s < 2; ++s)
#pragma unroll
    for (int gi = 0; gi < 4; ++gi) {
      const int c2 = 128 * gi + 32 * w + 16 * s + l15;
      bias2[s][gi] = bih2[c2] + bhh2[c2];
    }

  float c0v[4] = {0.f, 0.f, 0.f, 0.f};
  float c1v[4] = {0.f, 0.f, 0.f, 0.f};
  float c2v[2][4] = {{0.f, 0.f, 0.f, 0.f}, {0.f, 0.f, 0.f, 0.f}};

  // x prefetch (one step ahead)
  const float* xrow = x + (size_t)(r0 + l15) * 512 * 32 + k0;
  float4 nx0 = *(const float4*)xrow;
  float4 nx1 = *(const float4*)(xrow + 4);

  __syncthreads();

#pragma unroll 1
  for (int t = 0; t < 512; ++t) {
    const int p  = t & 1;
    const int rb = p ^ 1;

    float4 cx0 = nx0, cx1 = nx1;
    {
      const int tn = (t + 1 < 512) ? (t + 1) : 0;  // wraparound load, value unused
      const float* xp = xrow + (size_t)tn * 32;
      nx0 = *(const float4*)xp;
      nx1 = *(const float4*)(xp + 4);
    }

    // ================= layer 0 =================
    bf16x8 ax;
    ax[0] = f2bf(cx0.x); ax[1] = f2bf(cx0.y); ax[2] = f2bf(cx0.z); ax[3] = f2bf(cx0.w);
    ax[4] = f2bf(cx1.x); ax[5] = f2bf(cx1.y); ax[6] = f2bf(cx1.z); ax[7] = f2bf(cx1.w);

    bf16x8 a0 = *(const bf16x8*)&h0s[rb][l15][k0];
    bf16x8 a1 = *(const bf16x8*)&h0s[rb][l15][32 + k0];

    f32x4 acc[4];
#pragma unroll
    for (int gi = 0; gi < 4; ++gi) {
      f32x4 a = {bias0[gi], bias0[gi], bias0[gi], bias0[gi]};
      a = MF(ax, W0x[gi], a);
      a = MF(a0, W0h[gi][0], a);
      a = MF(a1, W0h[gi][1], a);
      acc[gi] = a;
    }
#pragma unroll
    for (int j = 0; j < 4; ++j) {
      float nc = fsig(acc[1][j]) * c0v[j] + fsig(acc[0][j]) * ftanh(acc[2][j]);
      c0v[j] = nc;
      h0s[p][4 * lg + j][16 * w + l15] = f2bf(fsig(acc[3][j]) * ftanh(nc));
    }
    __syncthreads();  // B1: h0(t) visible

    // ================= layer 1 =================
    a0 = *(const bf16x8*)&h0s[p][l15][k0];
    a1 = *(const bf16x8*)&h0s[p][l15][32 + k0];
    bf16x8 b0 = *(const bf16x8*)&h1s[rb][l15][k0];
    bf16x8 b1 = *(const bf16x8*)&h1s[rb][l15][32 + k0];
#pragma unroll
    for (int gi = 0; gi < 4; ++gi) {
      f32x4 a = {bias1[gi], bias1[gi], bias1[gi], bias1[gi]};
      a = MF(a0, W1a[gi][0], a);
      a = MF(a1, W1a[gi][1], a);
      a = MF(b0, W1h[gi][0], a);
      a = MF(b1, W1h[gi][1], a);
      acc[gi] = a;
    }
#pragma unroll
    for (int j = 0; j < 4; ++j) {
      float nc = fsig(acc[1][j]) * c1v[j] + fsig(acc[0][j]) * ftanh(acc[2][j]);
      c1v[j] = nc;
      h1s[p][4 * lg + j][16 * w + l15] = f2bf(fsig(acc[3][j]) * ftanh(nc));
    }
    __syncthreads();  // B2: h1(t) visible

    // ================= layer 2 =================
    a0 = *(const bf16x8*)&h1s[p][l15][k0];
    a1 = *(const bf16x8*)&h1s[p][l15][32 + k0];
    bf16x8 d0 = *(const bf16x8*)&h2s[rb][l15][k0];
    bf16x8 d1 = *(const bf16x8*)&h2s[rb][l15][32 + k0];
    bf16x8 d2 = *(const bf16x8*)&h2s[rb][l15][64 + k0];
    bf16x8 d3 = *(const bf16x8*)&h2s[rb][l15][96 + k0];

    f32x4 acc2[2][4];
#pragma unroll
    for (int s = 0; s < 2; ++s)
#pragma unroll
      for (int gi = 0; gi < 4; ++gi) {
        f32x4 a = {bias2[s][gi], bias2[s][gi], bias2[s][gi], bias2[s][gi]};
        a = MF(a0, W2a[s][gi][0], a);
        a = MF(a1, W2a[s][gi][1], a);
        a = MF(d0, W2h[s][gi][0], a);
        a = MF(d1, W2h[s][gi][1], a);
        a = MF(d2, W2h[s][gi][2], a);
        a = MF(d3, W2h[s][gi][3], a);
        acc2[s][gi] = a;
      }
#pragma unroll
    for (int s = 0; s < 2; ++s)
#pragma unroll
      for (int j = 0; j < 4; ++j) {
        float nc = fsig(acc2[s][1][j]) * c2v[s][j] + fsig(acc2[s][0][j]) * ftanh(acc2[s][2][j]);
        c2v[s][j] = nc;
        h2s[p][4 * lg + j][32 * w + 16 * s + l15] = f2bf(fsig(acc2[s][3][j]) * ftanh(nc));
      }
    __syncthreads();  // B3: h2(t) visible
  }

  // ================= final FC: out = h2 @ Wfc^T + bfc =================
  // last write was p = 511 & 1 = 1
  if (tid < 160) {
    const int r = tid / 10, o = tid - r * 10;
    float sum = bfc[o];
    for (int u = 0; u < 128; ++u) sum += bf2f(h2s[1][r][u]) * Wfc[o * 128 + u];
    out[(size_t)(r0 + r) * 10 + o] = sum;
  }
}

extern "C" void kernel_launch(void* const* d_in, const int* in_sizes, int n_in,
                              void* d_out, int out_size, void* d_ws, size_t ws_size,
                              hipStream_t stream) {
  const float* x    = (const float*)d_in[0];
  const float* Wih0 = (const float*)d_in[1];
  const float* Whh0 = (const float*)d_in[2];
  const float* bih0 = (const float*)d_in[3];
  const float* bhh0 = (const float*)d_in[4];
  const float* Wih1 = (const float*)d_in[5];
  const float* Whh1 = (const float*)d_in[6];
  const float* bih1 = (const float*)d_in[7];
  const float* bhh1 = (const float*)d_in[8];
  const float* Wih2 = (const float*)d_in[9];
  const float* Whh2 = (const float*)d_in[10];
  const float* bih2 = (const float*)d_in[11];
  const float* bhh2 = (const float*)d_in[12];
  const float* Wfc  = (const float*)d_in[13];
  const float* bfc  = (const float*)d_in[14];

  lstm_kernel<<<256, 256, 0, stream>>>(x, Wih0, Whh0, bih0, bhh0,
                                       Wih1, Whh1, bih1, bhh1,
                                       Wih2, Whh2, bih2, bhh2,
                                       Wfc, bfc, (float*)d_out);
}

// Round 3
// 1170.612 us; speedup vs baseline: 1.3291x; 1.0267x over previous
//
#include <hip/hip_runtime.h>

// B=4096, T=512, IN=32, H=[64,64,128], OUT=10
// 256 blocks x 512 threads (8 waves, 2/SIMD). Wave-specialized software pipeline:
//   waves 0-3 (G01): layer0(t) | layer1(t)
//   waves 4-7 (G23): layer2(t-1) MFMA | layer2(t-1) activations   (one step behind)
// Weights live in registers via a SHARED array WR[32] (union, not sum, across groups).
// Wih2 (G23's input weights) lives in LDS. h states double-buffered in LDS.

using f32x4  = __attribute__((ext_vector_type(4))) float;
using bf16x8 = __attribute__((ext_vector_type(8))) __bf16;

__device__ __forceinline__ __bf16 f2bf(float f) {
  unsigned u = __builtin_bit_cast(unsigned, f);
  unsigned short s = (unsigned short)((u + 0x7fffu + ((u >> 16) & 1u)) >> 16);
  return __builtin_bit_cast(__bf16, s);
}
__device__ __forceinline__ float bf2f(__bf16 b) {
  unsigned short s = __builtin_bit_cast(unsigned short, b);
  unsigned u = ((unsigned)s) << 16;
  return __builtin_bit_cast(float, u);
}
__device__ __forceinline__ float fsig(float x) {
  return __builtin_amdgcn_rcpf(1.0f + __builtin_amdgcn_exp2f(-1.442695041f * x));
}
__device__ __forceinline__ float ftanh(float x) {
  return 2.0f * __builtin_amdgcn_rcpf(1.0f + __builtin_amdgcn_exp2f(-2.885390082f * x)) - 1.0f;
}

#define MF(A, Bv, C) __builtin_amdgcn_mfma_f32_16x16x32_bf16((A), (Bv), (C), 0, 0, 0)

__device__ __forceinline__ bf16x8 ldw8(const float* p) {
  float4 v0 = *(const float4*)p;
  float4 v1 = *(const float4*)(p + 4);
  bf16x8 r;
  r[0] = f2bf(v0.x); r[1] = f2bf(v0.y); r[2] = f2bf(v0.z); r[3] = f2bf(v0.w);
  r[4] = f2bf(v1.x); r[5] = f2bf(v1.y); r[6] = f2bf(v1.z); r[7] = f2bf(v1.w);
  return r;
}

__global__ __launch_bounds__(512, 2)
void lstm_kernel(const float* __restrict__ x,
                 const float* __restrict__ Wih0, const float* __restrict__ Whh0,
                 const float* __restrict__ bih0, const float* __restrict__ bhh0,
                 const float* __restrict__ Wih1, const float* __restrict__ Whh1,
                 const float* __restrict__ bih1, const float* __restrict__ bhh1,
                 const float* __restrict__ Wih2, const float* __restrict__ Whh2,
                 const float* __restrict__ bih2, const float* __restrict__ bhh2,
                 const float* __restrict__ Wfc, const float* __restrict__ bfc,
                 float* __restrict__ out) {
  // double-buffered h states (stride 72/136 shorts -> 2-way bank aliasing only, free)
  __shared__ __align__(16) __bf16 h0s[2][16][72];
  __shared__ __align__(16) __bf16 h1s[2][16][72];
  __shared__ __align__(16) __bf16 h2s[2][16][136];
  // Wih2 staged in LDS [512][72] (row pad 8 -> 2-way aliasing only)
  __shared__ __align__(16) __bf16 wih2l[512][72];

  const int tid = threadIdx.x;
  const int w   = tid >> 6;      // wave 0..7
  const bool g01 = (w < 4);
  const int gw  = w & 3;         // wave id within group, 0..3
  const int l   = tid & 63;
  const int l15 = l & 15;
  const int lg  = l >> 4;
  const int k0  = lg * 8;
  const int r0  = blockIdx.x << 4;

  for (int i = tid; i < 2 * 16 * 72; i += 512) {
    (&h0s[0][0][0])[i] = __bf16(0.f);
    (&h1s[0][0][0])[i] = __bf16(0.f);
  }
  for (int i = tid; i < 2 * 16 * 136; i += 512) (&h2s[0][0][0])[i] = __bf16(0.f);
  for (int i = tid; i < 512 * 64; i += 512) {
    int row = i >> 6, col = i & 63;
    wih2l[row][col] = f2bf(Wih2[i]);
  }

  // ---- SHARED register arrays: allocation is the union across both groups ----
  // G01: WR[0..3]=Wih0, WR[4..11]=Whh0, WR[12..19]=Wih1, WR[20..27]=Whh1
  // G23: WR[0..31]=Whh2 (s,gi,kk -> 16s+4gi+kk)
  bf16x8 WR[32];
  f32x4  AC[8];     // G01: AC[0..3] reused l0 then l1; G23: AC[4s+gi], live across B1
  float  BI[8];     // G01: bias0[gi], bias1[4+gi]; G23: bias2 -> 4s+gi
  float  CS[8];     // G01: c0[j], c1[4+j]; G23: c2 -> 4s+j
#pragma unroll
  for (int i = 0; i < 8; ++i) CS[i] = 0.f;

  if (g01) {
#pragma unroll
    for (int gi = 0; gi < 4; ++gi) {
      const int row = 16 * (4 * gi + gw) + l15;
      WR[gi] = ldw8(Wih0 + (size_t)row * 32 + k0);
#pragma unroll
      for (int kb = 0; kb < 2; ++kb) {
        WR[4 + 2 * gi + kb]  = ldw8(Whh0 + (size_t)row * 64 + kb * 32 + k0);
        WR[12 + 2 * gi + kb] = ldw8(Wih1 + (size_t)row * 64 + kb * 32 + k0);
        WR[20 + 2 * gi + kb] = ldw8(Whh1 + (size_t)row * 64 + kb * 32 + k0);
      }
      const int c01 = 64 * gi + 16 * gw + l15;
      BI[gi]     = bih0[c01] + bhh0[c01];
      BI[4 + gi] = bih1[c01] + bhh1[c01];
    }
  } else {
#pragma unroll
    for (int s = 0; s < 2; ++s)
#pragma unroll
      for (int gi = 0; gi < 4; ++gi) {
        const int row = 16 * (8 * gi + 2 * gw + s) + l15;
#pragma unroll
        for (int kk = 0; kk < 4; ++kk)
          WR[16 * s + 4 * gi + kk] = ldw8(Whh2 + (size_t)row * 128 + kk * 32 + k0);
        const int c2 = 128 * gi + 32 * gw + 16 * s + l15;
        BI[4 * s + gi] = bih2[c2] + bhh2[c2];
      }
  }

  const float* xrow = x + (size_t)(r0 + l15) * 512 * 32 + k0;
  float4 nx0 = {0.f, 0.f, 0.f, 0.f}, nx1 = {0.f, 0.f, 0.f, 0.f};
  if (g01) { nx0 = *(const float4*)xrow; nx1 = *(const float4*)(xrow + 4); }

  __syncthreads();

#pragma unroll 1
  for (int t = 0; t <= 512; ++t) {
    const int pb = t & 1, rb = pb ^ 1;

    // ---------------- slot 1 ----------------
    if (g01) {
      if (t < 512) {
        // layer0(t): h0(t) = cell(x(t), h0(t-1))
        float4 cx0 = nx0, cx1 = nx1;
        const int tn = (t + 1) & 511;  // wraparound dummy at t=511
        nx0 = *(const float4*)(xrow + (size_t)tn * 32);
        nx1 = *(const float4*)(xrow + (size_t)tn * 32 + 4);

        bf16x8 ax;
        ax[0] = f2bf(cx0.x); ax[1] = f2bf(cx0.y); ax[2] = f2bf(cx0.z); ax[3] = f2bf(cx0.w);
        ax[4] = f2bf(cx1.x); ax[5] = f2bf(cx1.y); ax[6] = f2bf(cx1.z); ax[7] = f2bf(cx1.w);

        bf16x8 a0 = *(const bf16x8*)&h0s[rb][l15][k0];
        bf16x8 a1 = *(const bf16x8*)&h0s[rb][l15][32 + k0];
#pragma unroll
        for (int gi = 0; gi < 4; ++gi) {
          f32x4 a = {BI[gi], BI[gi], BI[gi], BI[gi]};
          a = MF(ax, WR[gi], a);
          a = MF(a0, WR[4 + 2 * gi], a);
          a = MF(a1, WR[5 + 2 * gi], a);
          AC[gi] = a;
        }
#pragma unroll
        for (int j = 0; j < 4; ++j) {
          float nc = fsig(AC[1][j]) * CS[j] + fsig(AC[0][j]) * ftanh(AC[2][j]);
          CS[j] = nc;
          h0s[pb][4 * lg + j][16 * gw + l15] = f2bf(fsig(AC[3][j]) * ftanh(nc));
        }
      }
    } else {
      if (t >= 1) {
        // layer2(t-1) MFMA: gates = Wih2*h1(t-1) + Whh2*h2(t-2) + b
        bf16x8 b0 = *(const bf16x8*)&h1s[rb][l15][k0];
        bf16x8 b1 = *(const bf16x8*)&h1s[rb][l15][32 + k0];
        bf16x8 d0 = *(const bf16x8*)&h2s[pb][l15][k0];
        bf16x8 d1 = *(const bf16x8*)&h2s[pb][l15][32 + k0];
        bf16x8 d2 = *(const bf16x8*)&h2s[pb][l15][64 + k0];
        bf16x8 d3 = *(const bf16x8*)&h2s[pb][l15][96 + k0];
#pragma unroll
        for (int s = 0; s < 2; ++s)
#pragma unroll
          for (int gi = 0; gi < 4; ++gi) {
            const int tile = 8 * gi + 2 * gw + s;
            bf16x8 wa0 = *(const bf16x8*)&wih2l[16 * tile + l15][k0];
            bf16x8 wa1 = *(const bf16x8*)&wih2l[16 * tile + l15][32 + k0];
            f32x4 a = {BI[4 * s + gi], BI[4 * s + gi], BI[4 * s + gi], BI[4 * s + gi]};
            a = MF(b0, wa0, a);
            a = MF(b1, wa1, a);
            a = MF(d0, WR[16 * s + 4 * gi + 0], a);
            a = MF(d1, WR[16 * s + 4 * gi + 1], a);
            a = MF(d2, WR[16 * s + 4 * gi + 2], a);
            a = MF(d3, WR[16 * s + 4 * gi + 3], a);
            AC[4 * s + gi] = a;
          }
      }
    }
    __syncthreads();  // B1: h0(t) visible to G01-l1

    // ---------------- slot 2 ----------------
    if (g01) {
      if (t < 512) {
        // layer1(t): h1(t) = cell(h0(t), h1(t-1))
        bf16x8 a0 = *(const bf16x8*)&h0s[pb][l15][k0];
        bf16x8 a1 = *(const bf16x8*)&h0s[pb][l15][32 + k0];
        bf16x8 b0 = *(const bf16x8*)&h1s[rb][l15][k0];
        bf16x8 b1 = *(const bf16x8*)&h1s[rb][l15][32 + k0];
#pragma unroll
        for (int gi = 0; gi < 4; ++gi) {
          f32x4 a = {BI[4 + gi], BI[4 + gi], BI[4 + gi], BI[4 + gi]};
          a = MF(a0, WR[12 + 2 * gi], a);
          a = MF(a1, WR[13 + 2 * gi], a);
          a = MF(b0, WR[20 + 2 * gi], a);
          a = MF(b1, WR[21 + 2 * gi], a);
          AC[gi] = a;
        }
#pragma unroll
        for (int j = 0; j < 4; ++j) {
          float nc = fsig(AC[1][j]) * CS[4 + j] + fsig(AC[0][j]) * ftanh(AC[2][j]);
          CS[4 + j] = nc;
          h1s[pb][4 * lg + j][16 * gw + l15] = f2bf(fsig(AC[3][j]) * ftanh(nc));
        }
      }
    } else {
      if (t >= 1) {
        // layer2(t-1) activations -> h2(t-1)
#pragma unroll
        for (int s = 0; s < 2; ++s)
#pragma unroll
          for (int j = 0; j < 4; ++j) {
            float nc = fsig(AC[4 * s + 1][j]) * CS[4 * s + j]
                     + fsig(AC[4 * s + 0][j]) * ftanh(AC[4 * s + 2][j]);
            CS[4 * s + j] = nc;
            h2s[rb][4 * lg + j][32 * gw + 16 * s + l15] = f2bf(fsig(AC[4 * s + 3][j]) * ftanh(nc));
          }
      }
    }
    __syncthreads();  // B2: h1(t), h2(t-1) visible
  }

  // ---- final FC: out = h2(511) @ Wfc^T + bfc;  h2(511) is in buffer 1 ----
  if (tid < 160) {
    const int r = tid / 10, o = tid - r * 10;
    float sum = bfc[o];
    for (int u = 0; u < 128; ++u) sum += bf2f(h2s[1][r][u]) * Wfc[o * 128 + u];
    out[(size_t)(r0 + r) * 10 + o] = sum;
  }
}

extern "C" void kernel_launch(void* const* d_in, const int* in_sizes, int n_in,
                              void* d_out, int out_size, void* d_ws, size_t ws_size,
                              hipStream_t stream) {
  const float* x    = (const float*)d_in[0];
  const float* Wih0 = (const float*)d_in[1];
  const float* Whh0 = (const float*)d_in[2];
  const float* bih0 = (const float*)d_in[3];
  const float* bhh0 = (const float*)d_in[4];
  const float* Wih1 = (const float*)d_in[5];
  const float* Whh1 = (const float*)d_in[6];
  const float* bih1 = (const float*)d_in[7];
  const float* bhh1 = (const float*)d_in[8];
  const float* Wih2 = (const float*)d_in[9];
  const float* Whh2 = (const float*)d_in[10];
  const float* bih2 = (const float*)d_in[11];
  const float* bhh2 = (const float*)d_in[12];
  const float* Wfc  = (const float*)d_in[13];
  const float* bfc  = (const float*)d_in[14];

  lstm_kernel<<<256, 512, 0, stream>>>(x, Wih0, Whh0, bih0, bhh0,
                                       Wih1, Whh1, bih1, bhh1,
                                       Wih2, Whh2, bih2, bhh2,
                                       Wfc, bfc, (float*)d_out);
}

// Round 5
// 1154.158 us; speedup vs baseline: 1.3480x; 1.0143x over previous
//
#include <hip/hip_runtime.h>

// B=4096, T=512, IN=32, H=[64,64,128], OUT=10
// 256 blocks (1/CU) x 256 threads (4 waves = 1 wave/SIMD -> 512-reg UNIFIED budget).
// Weights register-resident: W0x/W0h in arch VGPRs (builtin MFMA), W1a/W1h/W2a/W2h
// in AGPRs via inline-asm MFMA ("a" constraints, 64 slots = 256 AGPRs).
// Inline-asm MFMA needs MANUAL hazard handling (compiler can't see into asm):
//   - chain head: s_nop 2 before mfma (VALU bias-splat write -> SrcC read)
//   - chain tail: s_nop 7 x2 fence, operand-pinned, before VALU reads of acc.

using f32x4  = __attribute__((ext_vector_type(4))) float;
using bf16x8 = __attribute__((ext_vector_type(8))) __bf16;

__device__ __forceinline__ __bf16 f2bf(float f) {
  unsigned u = __builtin_bit_cast(unsigned, f);
  unsigned short s = (unsigned short)((u + 0x7fffu + ((u >> 16) & 1u)) >> 16);
  return __builtin_bit_cast(__bf16, s);
}
__device__ __forceinline__ float bf2f(__bf16 b) {
  unsigned short s = __builtin_bit_cast(unsigned short, b);
  unsigned u = ((unsigned)s) << 16;
  return __builtin_bit_cast(float, u);
}
__device__ __forceinline__ float fsig(float x) {
  return __builtin_amdgcn_rcpf(1.0f + __builtin_amdgcn_exp2f(-1.442695041f * x));
}
__device__ __forceinline__ float ftanh(float x) {
  return 2.0f * __builtin_amdgcn_rcpf(1.0f + __builtin_amdgcn_exp2f(-2.885390082f * x)) - 1.0f;
}

// builtin MFMA (weights in arch VGPRs; compiler handles hazards)
#define MF(A, Bv, C) __builtin_amdgcn_mfma_f32_16x16x32_bf16((A), (Bv), (C), 0, 0, 0)
// asm MFMA, weight pinned to AGPR — chain-interior form (C comes from prior MFMA)
#define MFA(A, Ba, C) asm("v_mfma_f32_16x16x32_bf16 %0, %1, %2, %0" \
                          : "+v"(C) : "v"(A), "a"(Ba))
// chain-head form: C was just written by VALU (bias splat) -> 2 wait states first
#define MFA_F(A, Ba, C) asm("s_nop 2\n\tv_mfma_f32_16x16x32_bf16 %0, %1, %2, %0" \
                            : "+v"(C) : "v"(A), "a"(Ba))
// MFMA-D -> VALU-read fence, operand-pinned so it sits between writes and reads
#define FENCE4(c0, c1, c2, c3) \
  asm volatile("s_nop 7\n\ts_nop 7" : "+v"(c0), "+v"(c1), "+v"(c2), "+v"(c3))
#define FENCE8(c0, c1, c2, c3, c4, c5, c6, c7)                                  \
  asm volatile("s_nop 7\n\ts_nop 7" : "+v"(c0), "+v"(c1), "+v"(c2), "+v"(c3),   \
                                      "+v"(c4), "+v"(c5), "+v"(c6), "+v"(c7))

__device__ __forceinline__ bf16x8 ldw8(const float* p) {
  float4 v0 = *(const float4*)p;
  float4 v1 = *(const float4*)(p + 4);
  bf16x8 r;
  r[0] = f2bf(v0.x); r[1] = f2bf(v0.y); r[2] = f2bf(v0.z); r[3] = f2bf(v0.w);
  r[4] = f2bf(v1.x); r[5] = f2bf(v1.y); r[6] = f2bf(v1.z); r[7] = f2bf(v1.w);
  return r;
}

__global__ __launch_bounds__(256, 1)
void lstm_kernel(const float* __restrict__ x,
                 const float* __restrict__ Wih0, const float* __restrict__ Whh0,
                 const float* __restrict__ bih0, const float* __restrict__ bhh0,
                 const float* __restrict__ Wih1, const float* __restrict__ Whh1,
                 const float* __restrict__ bih1, const float* __restrict__ bhh1,
                 const float* __restrict__ Wih2, const float* __restrict__ Whh2,
                 const float* __restrict__ bih2, const float* __restrict__ bhh2,
                 const float* __restrict__ Wfc, const float* __restrict__ bfc,
                 float* __restrict__ out) {
  __shared__ __align__(16) __bf16 h0s[2][16][72];
  __shared__ __align__(16) __bf16 h1s[2][16][72];
  __shared__ __align__(16) __bf16 h2s[2][16][136];

  const int tid = threadIdx.x;
  const int w   = tid >> 6;   // wave 0..3
  const int l   = tid & 63;
  const int l15 = l & 15;
  const int lg  = l >> 4;     // 0..3
  const int k0  = lg * 8;
  const int r0  = blockIdx.x << 4;

  for (int i = tid; i < 2 * 16 * 72; i += 256) {
    (&h0s[0][0][0])[i] = __bf16(0.f);
    (&h1s[0][0][0])[i] = __bf16(0.f);
  }
  for (int i = tid; i < 2 * 16 * 136; i += 256) (&h2s[0][0][0])[i] = __bf16(0.f);

  // ---- weight slices ----
  bf16x8 W0x[4];        // VGPR: Wih0 [gi], tile=4gi+w
  bf16x8 W0h[4][2];     // VGPR: Whh0 [gi][kb]
  bf16x8 W1a[4][2];     // AGPR: Wih1
  bf16x8 W1h[4][2];     // AGPR: Whh1
  bf16x8 W2a[2][4][2];  // AGPR: Wih2, tile=8gi+2w+s
  bf16x8 W2h[2][4][4];  // AGPR: Whh2
#pragma unroll
  for (int gi = 0; gi < 4; ++gi) {
    const int row = 16 * (4 * gi + w) + l15;
    W0x[gi] = ldw8(Wih0 + (size_t)row * 32 + k0);
#pragma unroll
    for (int kb = 0; kb < 2; ++kb) {
      W0h[gi][kb] = ldw8(Whh0 + (size_t)row * 64 + kb * 32 + k0);
      W1a[gi][kb] = ldw8(Wih1 + (size_t)row * 64 + kb * 32 + k0);
      W1h[gi][kb] = ldw8(Whh1 + (size_t)row * 64 + kb * 32 + k0);
    }
  }
#pragma unroll
  for (int s = 0; s < 2; ++s)
#pragma unroll
    for (int gi = 0; gi < 4; ++gi) {
      const int row = 16 * (8 * gi + 2 * w + s) + l15;
#pragma unroll
      for (int kb = 0; kb < 2; ++kb)
        W2a[s][gi][kb] = ldw8(Wih2 + (size_t)row * 64 + kb * 32 + k0);
#pragma unroll
      for (int kk = 0; kk < 4; ++kk)
        W2h[s][gi][kk] = ldw8(Whh2 + (size_t)row * 128 + kk * 32 + k0);
    }

  float bias0[4], bias1[4], bias2[2][4];
#pragma unroll
  for (int gi = 0; gi < 4; ++gi) {
    const int c01 = 64 * gi + 16 * w + l15;
    bias0[gi] = bih0[c01] + bhh0[c01];
    bias1[gi] = bih1[c01] + bhh1[c01];
  }
#pragma unroll
  for (int s = 0; s < 2; ++s)
#pragma unroll
    for (int gi = 0; gi < 4; ++gi) {
      const int c2 = 128 * gi + 32 * w + 16 * s + l15;
      bias2[s][gi] = bih2[c2] + bhh2[c2];
    }

  float c0v[4] = {0.f, 0.f, 0.f, 0.f};
  float c1v[4] = {0.f, 0.f, 0.f, 0.f};
  float c2v[2][4] = {{0.f, 0.f, 0.f, 0.f}, {0.f, 0.f, 0.f, 0.f}};

  const float* xrow = x + (size_t)(r0 + l15) * 512 * 32 + k0;
  float4 nx0 = *(const float4*)xrow;
  float4 nx1 = *(const float4*)(xrow + 4);

  __syncthreads();

#pragma unroll 1
  for (int t = 0; t < 512; ++t) {
    const int p  = t & 1;
    const int rb = p ^ 1;

    float4 cx0 = nx0, cx1 = nx1;
    {
      const int tn = (t + 1) & 511;  // wraparound dummy load at t=511
      const float* xp = xrow + (size_t)tn * 32;
      nx0 = *(const float4*)xp;
      nx1 = *(const float4*)(xp + 4);
    }

    // ================= layer 0 (builtin MFMA, VGPR weights) =================
    bf16x8 ax;
    ax[0] = f2bf(cx0.x); ax[1] = f2bf(cx0.y); ax[2] = f2bf(cx0.z); ax[3] = f2bf(cx0.w);
    ax[4] = f2bf(cx1.x); ax[5] = f2bf(cx1.y); ax[6] = f2bf(cx1.z); ax[7] = f2bf(cx1.w);

    bf16x8 a0 = *(const bf16x8*)&h0s[rb][l15][k0];
    bf16x8 a1 = *(const bf16x8*)&h0s[rb][l15][32 + k0];

    f32x4 acc[4];
#pragma unroll
    for (int gi = 0; gi < 4; ++gi) {
      f32x4 a = {bias0[gi], bias0[gi], bias0[gi], bias0[gi]};
      a = MF(ax, W0x[gi], a);
      a = MF(a0, W0h[gi][0], a);
      a = MF(a1, W0h[gi][1], a);
      acc[gi] = a;
    }
#pragma unroll
    for (int j = 0; j < 4; ++j) {
      float nc = fsig(acc[1][j]) * c0v[j] + fsig(acc[0][j]) * ftanh(acc[2][j]);
      c0v[j] = nc;
      h0s[p][4 * lg + j][16 * w + l15] = f2bf(fsig(acc[3][j]) * ftanh(nc));
    }
    __syncthreads();  // B1: h0(t) visible

    // ================= layer 1 (asm MFMA, AGPR weights) =================
    a0 = *(const bf16x8*)&h0s[p][l15][k0];
    a1 = *(const bf16x8*)&h0s[p][l15][32 + k0];
    bf16x8 b0 = *(const bf16x8*)&h1s[rb][l15][k0];
    bf16x8 b1 = *(const bf16x8*)&h1s[rb][l15][32 + k0];
#pragma unroll
    for (int gi = 0; gi < 4; ++gi) {
      f32x4 a = {bias1[gi], bias1[gi], bias1[gi], bias1[gi]};
      MFA_F(a0, W1a[gi][0], a);
      MFA(a1, W1a[gi][1], a);
      MFA(b0, W1h[gi][0], a);
      MFA(b1, W1h[gi][1], a);
      acc[gi] = a;
    }
    FENCE4(acc[0], acc[1], acc[2], acc[3]);
#pragma unroll
    for (int j = 0; j < 4; ++j) {
      float nc = fsig(acc[1][j]) * c1v[j] + fsig(acc[0][j]) * ftanh(acc[2][j]);
      c1v[j] = nc;
      h1s[p][4 * lg + j][16 * w + l15] = f2bf(fsig(acc[3][j]) * ftanh(nc));
    }
    __syncthreads();  // B2: h1(t) visible

    // ================= layer 2 (asm MFMA, AGPR weights) =================
    a0 = *(const bf16x8*)&h1s[p][l15][k0];
    a1 = *(const bf16x8*)&h1s[p][l15][32 + k0];
    bf16x8 d0 = *(const bf16x8*)&h2s[rb][l15][k0];
    bf16x8 d1 = *(const bf16x8*)&h2s[rb][l15][32 + k0];
    bf16x8 d2 = *(const bf16x8*)&h2s[rb][l15][64 + k0];
    bf16x8 d3 = *(const bf16x8*)&h2s[rb][l15][96 + k0];

    f32x4 acc2[2][4];
#pragma unroll
    for (int s = 0; s < 2; ++s)
#pragma unroll
      for (int gi = 0; gi < 4; ++gi) {
        f32x4 a = {bias2[s][gi], bias2[s][gi], bias2[s][gi], bias2[s][gi]};
        MFA_F(a0, W2a[s][gi][0], a);
        MFA(a1, W2a[s][gi][1], a);
        MFA(d0, W2h[s][gi][0], a);
        MFA(d1, W2h[s][gi][1], a);
        MFA(d2, W2h[s][gi][2], a);
        MFA(d3, W2h[s][gi][3], a);
        acc2[s][gi] = a;
      }
    FENCE8(acc2[0][0], acc2[0][1], acc2[0][2], acc2[0][3],
           acc2[1][0], acc2[1][1], acc2[1][2], acc2[1][3]);
#pragma unroll
    for (int s = 0; s < 2; ++s)
#pragma unroll
      for (int j = 0; j < 4; ++j) {
        float nc = fsig(acc2[s][1][j]) * c2v[s][j] + fsig(acc2[s][0][j]) * ftanh(acc2[s][2][j]);
        c2v[s][j] = nc;
        h2s[p][4 * lg + j][32 * w + 16 * s + l15] = f2bf(fsig(acc2[s][3][j]) * ftanh(nc));
      }
    __syncthreads();  // B3: h2(t) visible
  }

  // ================= final FC: out = h2(511) @ Wfc^T + bfc (buffer 1) ==========
  if (tid < 160) {
    const int r = tid / 10, o = tid - r * 10;
    float sum = bfc[o];
    for (int u = 0; u < 128; ++u) sum += bf2f(h2s[1][r][u]) * Wfc[o * 128 + u];
    out[(size_t)(r0 + r) * 10 + o] = sum;
  }
}

extern "C" void kernel_launch(void* const* d_in, const int* in_sizes, int n_in,
                              void* d_out, int out_size, void* d_ws, size_t ws_size,
                              hipStream_t stream) {
  const float* x    = (const float*)d_in[0];
  const float* Wih0 = (const float*)d_in[1];
  const float* Whh0 = (const float*)d_in[2];
  const float* bih0 = (const float*)d_in[3];
  const float* bhh0 = (const float*)d_in[4];
  const float* Wih1 = (const float*)d_in[5];
  const float* Whh1 = (const float*)d_in[6];
  const float* bih1 = (const float*)d_in[7];
  const float* bhh1 = (const float*)d_in[8];
  const float* Wih2 = (const float*)d_in[9];
  const float* Whh2 = (const float*)d_in[10];
  const float* bih2 = (const float*)d_in[11];
  const float* bhh2 = (const float*)d_in[12];
  const float* Wfc  = (const float*)d_in[13];
  const float* bfc  = (const float*)d_in[14];

  lstm_kernel<<<256, 256, 0, stream>>>(x, Wih0, Whh0, bih0, bhh0,
                                       Wih1, Whh1, bih1, bhh1,
                                       Wih2, Whh2, bih2, bhh2,
                                       Wfc, bfc, (float*)d_out);
}